// Round 6
// baseline (168.927 us; speedup 1.0000x reference)
//
#include <hip/hip_runtime.h>

// MeanAggregator on MI355X.
// memset -> [Wprep|count] -> scan_local -> scan_blocks -> place -> mlp -> aggregate.

constexpr int D = 128;
constexpr int SCAN_CHUNK = 1024;

typedef __attribute__((ext_vector_type(8))) short short8;
typedef __attribute__((ext_vector_type(4))) float f32x4;

__device__ __forceinline__ unsigned short f2bf(float x) {
    unsigned int u = __float_as_uint(x);
    u += 0x7fffu + ((u >> 16) & 1u);
    return (unsigned short)(u >> 16);
}
__device__ __forceinline__ float bflo(unsigned int u) { return __uint_as_float(u << 16); }
__device__ __forceinline__ float bfhi(unsigned int u) { return __uint_as_float(u & 0xffff0000u); }
__device__ __forceinline__ float fast_tanh(float x) {
    float e = exp2f(x * 2.885390081777927f);
    return fmaf(-2.0f, __builtin_amdgcn_rcpf(e + 1.0f), 1.0f);
}

// ---- prep: W transpose->bf16 (blocks 0..63) | edge count (rest) ----
__global__ __launch_bounds__(256) void k_prep_count(const float* __restrict__ W1,
                                                    const float* __restrict__ W2,
                                                    unsigned short* __restrict__ Wt1,
                                                    unsigned short* __restrict__ Wt2,
                                                    const int* __restrict__ src,
                                                    const int* __restrict__ dst,
                                                    int* __restrict__ count,
                                                    int* __restrict__ selfc, int E) {
    int b = blockIdx.x;
    if (b < 64) {
        int t = b * 256 + threadIdx.x;  // t = k*D+n, coalesced read
        int k = t >> 7, nn = t & 127;
        Wt1[nn * D + k] = f2bf(W1[t]);
        Wt2[nn * D + k] = f2bf(W2[t]);
    } else {
        int e = (b - 64) * 256 + threadIdx.x;
        if (e < E) {
            int s = src[e];
            atomicAdd(&count[s], 1);
            if (s == dst[e]) atomicAdd(&selfc[s], 1);
        }
    }
}

// ---- scan stage 1: local exclusive scan; degree; count->0 (cursor) ----
__global__ __launch_bounds__(256) void k_scan_local(int* __restrict__ count,
                                                    const int* __restrict__ selfc,
                                                    const int* __restrict__ indp,
                                                    float* __restrict__ degree,
                                                    int* __restrict__ row_ptr,
                                                    int* __restrict__ block_sums, int n) {
    __shared__ int s[256];
    const int t = threadIdx.x;
    const int base = blockIdx.x * SCAN_CHUNK + t * 4;
    const float mask = (indp[0] < 2) ? 1.0f : 0.0f;  // MASK = (1,1,0,0)
    int v[4];
#pragma unroll
    for (int j = 0; j < 4; ++j) {
        v[j] = 0;
        if (base + j < n) {
            int c = count[base + j];
            v[j] = c;
            degree[base + j] = (float)c + (mask - 1.0f) * (float)selfc[base + j];
            count[base + j] = 0;
        }
    }
    int sum4 = v[0] + v[1] + v[2] + v[3];
    s[t] = sum4;
    __syncthreads();
#pragma unroll
    for (int off = 1; off < 256; off <<= 1) {
        int x = (t >= off) ? s[t - off] : 0;
        __syncthreads();
        s[t] += x;
        __syncthreads();
    }
    int excl = s[t] - sum4;
    if (t == 255) block_sums[blockIdx.x] = s[255];
#pragma unroll
    for (int j = 0; j < 4; ++j) {
        if (base + j < n) row_ptr[base + j] = excl;
        excl += v[j];
    }
}

// ---- scan stage 2: exclusive-scan block sums (in place) ----
__global__ __launch_bounds__(128) void k_scan_blocks(int* __restrict__ block_sums, int nb) {
    __shared__ int s[128];
    const int t = threadIdx.x;
    int v = (t < nb) ? block_sums[t] : 0;
    s[t] = v;
    __syncthreads();
#pragma unroll
    for (int off = 1; off < 128; off <<= 1) {
        int x = (t >= off) ? s[t - off] : 0;
        __syncthreads();
        s[t] += x;
        __syncthreads();
    }
    if (t < nb) block_sums[t] = s[t] - v;
}

// ---- place: pairs[pos] = (dst, degree[dst]*W_edge[e]) in CSR-by-src order ----
__global__ __launch_bounds__(256) void k_place(const int* __restrict__ src,
                                               const int* __restrict__ dst,
                                               const float* __restrict__ W_edge,
                                               const float* __restrict__ degree,
                                               const int* __restrict__ row_ptr,
                                               const int* __restrict__ bsum,
                                               int* __restrict__ cursor,
                                               float2* __restrict__ pairs, int E) {
    int e = blockIdx.x * 256 + threadIdx.x;
    if (e >= E) return;
    int s = src[e];
    int d = dst[e];
    int pos = row_ptr[s] + bsum[s >> 10] + atomicAdd(&cursor[s], 1);
    float2 p;
    p.x = __int_as_float(d);
    p.y = degree[d] * W_edge[e];
    pairs[pos] = p;
}

// ---- MLP: 64 rows/block, 4 waves x 16 rows, barrier-free, W direct from global ----
__global__ __launch_bounds__(256) void k_mlp(const float* __restrict__ feat,
                                             const unsigned short* __restrict__ Wt1,
                                             const unsigned short* __restrict__ Wt2,
                                             const float* __restrict__ b1,
                                             const float* __restrict__ b2,
                                             unsigned short* __restrict__ hbf, int n) {
    __shared__ unsigned short sT[64 * D];  // 16 KB; each wave uses its own 4 KB
    const int t = threadIdx.x;
    const int lane = t & 63;
    const int w = t >> 6;
    const int rl0 = w * 16;                    // wave's LDS row base
    const int row0 = blockIdx.x * 64 + rl0;    // wave's global row base
    const int rA = lane & 15;
    const int ks = (lane >> 4) * 8;

    f32x4 acc[8];
#pragma unroll
    for (int nf = 0; nf < 8; ++nf) acc[nf] = (f32x4){0.f, 0.f, 0.f, 0.f};

    // GEMM1: A direct from feat (f32->bf16 in reg), B direct from Wt1
#pragma unroll
    for (int kc = 0; kc < 4; ++kc) {
        int gr = row0 + rA;
        float4 f0 = make_float4(0.f, 0.f, 0.f, 0.f), f1 = f0;
        if (gr < n) {
            const float* fp = &feat[(size_t)gr * D + kc * 32 + ks];
            f0 = *(const float4*)fp;
            f1 = *(const float4*)(fp + 4);
        }
        short8 a;
        a[0] = (short)f2bf(f0.x); a[1] = (short)f2bf(f0.y);
        a[2] = (short)f2bf(f0.z); a[3] = (short)f2bf(f0.w);
        a[4] = (short)f2bf(f1.x); a[5] = (short)f2bf(f1.y);
        a[6] = (short)f2bf(f1.z); a[7] = (short)f2bf(f1.w);
#pragma unroll
        for (int nf = 0; nf < 8; ++nf) {
            short8 b = *(const short8*)&Wt1[(nf * 16 + rA) * D + kc * 32 + ks];
            acc[nf] = __builtin_amdgcn_mfma_f32_16x16x32_bf16(a, b, acc[nf], 0, 0, 0);
        }
    }

    // tanh -> own 16 LDS rows (swizzled); wave-local
#pragma unroll
    for (int nf = 0; nf < 8; ++nf) {
        const int col = nf * 16 + rA;
        const float bias = b1[col];
#pragma unroll
        for (int i = 0; i < 4; ++i) {
            const int rl = rl0 + (lane >> 4) * 4 + i;
            unsigned short hv = f2bf(fast_tanh(acc[nf][i] + bias));
            *(unsigned short*)((char*)sT + ((rl * 256 + col * 2) ^ ((rl & 7) << 4))) = hv;
        }
    }

#pragma unroll
    for (int nf = 0; nf < 8; ++nf) acc[nf] = (f32x4){0.f, 0.f, 0.f, 0.f};

    // GEMM2: A from own LDS rows, B direct from Wt2
#pragma unroll
    for (int kc = 0; kc < 4; ++kc) {
        const int kb = (kc * 32 + ks) * 2;
        const int ra0 = rl0 + rA;
        short8 a0 = *(short8*)((char*)sT + ((ra0 * 256 + kb) ^ ((ra0 & 7) << 4)));
#pragma unroll
        for (int nf = 0; nf < 8; ++nf) {
            short8 b = *(const short8*)&Wt2[(nf * 16 + rA) * D + kc * 32 + ks];
            acc[nf] = __builtin_amdgcn_mfma_f32_16x16x32_bf16(a0, b, acc[nf], 0, 0, 0);
        }
    }

    // epilogue: +b2 -> bf16 -> own LDS rows
#pragma unroll
    for (int nf = 0; nf < 8; ++nf) {
        const int col = nf * 16 + rA;
        const float bias = b2[col];
#pragma unroll
        for (int i = 0; i < 4; ++i) {
            const int rl = rl0 + (lane >> 4) * 4 + i;
            unsigned short hv = f2bf(acc[nf][i] + bias);
            *(unsigned short*)((char*)sT + ((rl * 256 + col * 2) ^ ((rl & 7) << 4))) = hv;
        }
    }

    // coalesced store of own 16 rows
    for (int c = lane; c < 256; c += 64) {
        int r = c >> 4, k0 = (c & 15) * 8;
        int gr = row0 + r;
        if (gr < n) {
            int rl = rl0 + r;
            short8 v = *(short8*)((char*)sT + ((rl * 256 + k0 * 2) ^ ((rl & 7) << 4)));
            *(short8*)&hbf[(size_t)gr * D + k0] = v;
        }
    }
}

// ---- aggregate: 8 lanes/node (32 B h per lane); lane-parallel pairs + shfl ----
__global__ __launch_bounds__(256) void k_aggregate(const int* __restrict__ row_ptr,
                                                   const int* __restrict__ bsum,
                                                   const float2* __restrict__ pairs,
                                                   const unsigned short* __restrict__ hbf,
                                                   float* __restrict__ out, int n, int E) {
    long long tid = (long long)blockIdx.x * 256 + threadIdx.x;
    int node = (int)(tid >> 3);
    int li = (int)(tid & 7);
    int lane = threadIdx.x & 63;
    if (node >= n) return;
    int beg = row_ptr[node] + bsum[node >> 10];
    int end = (node + 1 == n) ? E : row_ptr[node + 1] + bsum[(node + 1) >> 10];

    float acc[16];
#pragma unroll
    for (int j = 0; j < 16; ++j) acc[j] = 0.f;
    float rsp = 0.f;
    const int gbase = lane & 56;  // first lane of this 8-lane group

    for (int base = beg; base < end; base += 8) {
        int m = end - base;
        m = (m > 8) ? 8 : m;
        float2 p = make_float2(0.f, 0.f);
        if (li < m) p = pairs[base + li];
        rsp += p.y;
        int i = 0;
        for (; i + 1 < m; i += 2) {
            int d0 = __float_as_int(__shfl(p.x, gbase + i));
            float w0 = __shfl(p.y, gbase + i);
            int d1 = __float_as_int(__shfl(p.x, gbase + i + 1));
            float w1 = __shfl(p.y, gbase + i + 1);
            const uint4* hp0 = (const uint4*)&hbf[(size_t)d0 * D + li * 16];
            const uint4* hp1 = (const uint4*)&hbf[(size_t)d1 * D + li * 16];
            uint4 h0a = hp0[0], h0b = hp0[1];
            uint4 h1a = hp1[0], h1b = hp1[1];
            acc[0]  = fmaf(w0, bflo(h0a.x), acc[0]);  acc[1]  = fmaf(w0, bfhi(h0a.x), acc[1]);
            acc[2]  = fmaf(w0, bflo(h0a.y), acc[2]);  acc[3]  = fmaf(w0, bfhi(h0a.y), acc[3]);
            acc[4]  = fmaf(w0, bflo(h0a.z), acc[4]);  acc[5]  = fmaf(w0, bfhi(h0a.z), acc[5]);
            acc[6]  = fmaf(w0, bflo(h0a.w), acc[6]);  acc[7]  = fmaf(w0, bfhi(h0a.w), acc[7]);
            acc[8]  = fmaf(w0, bflo(h0b.x), acc[8]);  acc[9]  = fmaf(w0, bfhi(h0b.x), acc[9]);
            acc[10] = fmaf(w0, bflo(h0b.y), acc[10]); acc[11] = fmaf(w0, bfhi(h0b.y), acc[11]);
            acc[12] = fmaf(w0, bflo(h0b.z), acc[12]); acc[13] = fmaf(w0, bfhi(h0b.z), acc[13]);
            acc[14] = fmaf(w0, bflo(h0b.w), acc[14]); acc[15] = fmaf(w0, bfhi(h0b.w), acc[15]);
            acc[0]  = fmaf(w1, bflo(h1a.x), acc[0]);  acc[1]  = fmaf(w1, bfhi(h1a.x), acc[1]);
            acc[2]  = fmaf(w1, bflo(h1a.y), acc[2]);  acc[3]  = fmaf(w1, bfhi(h1a.y), acc[3]);
            acc[4]  = fmaf(w1, bflo(h1a.z), acc[4]);  acc[5]  = fmaf(w1, bfhi(h1a.z), acc[5]);
            acc[6]  = fmaf(w1, bflo(h1a.w), acc[6]);  acc[7]  = fmaf(w1, bfhi(h1a.w), acc[7]);
            acc[8]  = fmaf(w1, bflo(h1b.x), acc[8]);  acc[9]  = fmaf(w1, bfhi(h1b.x), acc[9]);
            acc[10] = fmaf(w1, bflo(h1b.y), acc[10]); acc[11] = fmaf(w1, bfhi(h1b.y), acc[11]);
            acc[12] = fmaf(w1, bflo(h1b.z), acc[12]); acc[13] = fmaf(w1, bfhi(h1b.z), acc[13]);
            acc[14] = fmaf(w1, bflo(h1b.w), acc[14]); acc[15] = fmaf(w1, bfhi(h1b.w), acc[15]);
        }
        if (i < m) {
            int d0 = __float_as_int(__shfl(p.x, gbase + i));
            float w0 = __shfl(p.y, gbase + i);
            const uint4* hp0 = (const uint4*)&hbf[(size_t)d0 * D + li * 16];
            uint4 h0a = hp0[0], h0b = hp0[1];
            acc[0]  = fmaf(w0, bflo(h0a.x), acc[0]);  acc[1]  = fmaf(w0, bfhi(h0a.x), acc[1]);
            acc[2]  = fmaf(w0, bflo(h0a.y), acc[2]);  acc[3]  = fmaf(w0, bfhi(h0a.y), acc[3]);
            acc[4]  = fmaf(w0, bflo(h0a.z), acc[4]);  acc[5]  = fmaf(w0, bfhi(h0a.z), acc[5]);
            acc[6]  = fmaf(w0, bflo(h0a.w), acc[6]);  acc[7]  = fmaf(w0, bfhi(h0a.w), acc[7]);
            acc[8]  = fmaf(w0, bflo(h0b.x), acc[8]);  acc[9]  = fmaf(w0, bfhi(h0b.x), acc[9]);
            acc[10] = fmaf(w0, bflo(h0b.y), acc[10]); acc[11] = fmaf(w0, bfhi(h0b.y), acc[11]);
            acc[12] = fmaf(w0, bflo(h0b.z), acc[12]); acc[13] = fmaf(w0, bfhi(h0b.z), acc[13]);
            acc[14] = fmaf(w0, bflo(h0b.w), acc[14]); acc[15] = fmaf(w0, bfhi(h0b.w), acc[15]);
        }
    }
    rsp += __shfl_xor(rsp, 1);
    rsp += __shfl_xor(rsp, 2);
    rsp += __shfl_xor(rsp, 4);
    rsp = (rsp == 0.f) ? 1.f : rsp;
    float inv = 1.0f / rsp;
    float* op = &out[(size_t)node * D + li * 16];
#pragma unroll
    for (int q = 0; q < 4; ++q) {
        float4 o;
        o.x = acc[q * 4 + 0] * inv;
        o.y = acc[q * 4 + 1] * inv;
        o.z = acc[q * 4 + 2] * inv;
        o.w = acc[q * 4 + 3] * inv;
        *(float4*)(op + q * 4) = o;
    }
}

extern "C" void kernel_launch(void* const* d_in, const int* in_sizes, int n_in,
                              void* d_out, int out_size, void* d_ws, size_t ws_size,
                              hipStream_t stream) {
    const float* feat   = (const float*)d_in[0];
    const float* W_edge = (const float*)d_in[1];
    const float* W1     = (const float*)d_in[2];
    const float* b1     = (const float*)d_in[3];
    const float* W2     = (const float*)d_in[4];
    const float* b2     = (const float*)d_in[5];
    const int* edge_src = (const int*)d_in[6];
    const int* edge_dst = (const int*)d_in[7];
    const int* indp     = (const int*)d_in[8];

    const int n = in_sizes[0] / D;   // 100000
    const int E = in_sizes[6];       // 600000
    const int nb = (n + SCAN_CHUNK - 1) / SCAN_CHUNK;  // 98

    // ws (16B-aligned front): Wt1 u16[D*D] | Wt2 u16[D*D] | degree f[n] | pairs f2[E] |
    //     hbf u16[n*D] | count i[n] | selfc i[n] | row_ptr i[n+1] | bsum i[128]
    char* ws = (char*)d_ws;
    unsigned short* Wt1 = (unsigned short*)ws;
    unsigned short* Wt2 = Wt1 + D * D;
    float* degree       = (float*)(Wt2 + D * D);
    float2* pairs       = (float2*)(degree + n);
    unsigned short* hbf = (unsigned short*)(pairs + E);
    int* count          = (int*)(hbf + (size_t)n * D);
    int* selfc          = count + n;
    int* row_ptr        = selfc + n;
    int* block_sums     = row_ptr + (n + 1);

    hipMemsetAsync(count, 0, (size_t)2 * n * sizeof(int), stream);

    const int eb = (E + 255) / 256;              // 2344
    k_prep_count<<<64 + eb, 256, 0, stream>>>(W1, W2, Wt1, Wt2,
                                              edge_src, edge_dst, count, selfc, E);

    k_scan_local<<<nb, 256, 0, stream>>>(count, selfc, indp, degree, row_ptr, block_sums, n);
    k_scan_blocks<<<1, 128, 0, stream>>>(block_sums, nb);

    k_place<<<eb, 256, 0, stream>>>(edge_src, edge_dst, W_edge, degree, row_ptr, block_sums,
                                    count, pairs, E);

    k_mlp<<<(n + 63) / 64, 256, 0, stream>>>(feat, Wt1, Wt2, b1, b2, hbf, n);

    long long athreads = (long long)n * 8;
    k_aggregate<<<(int)((athreads + 255) / 256), 256, 0, stream>>>(row_ptr, block_sums, pairs,
                                                                   hbf, (float*)d_out, n, E);
}

// Round 7
// 152.006 us; speedup vs baseline: 1.1113x; 1.1113x over previous
//
#include <hip/hip_runtime.h>

// MeanAggregator on MI355X.
// [Wprep|zero] -> count -> scan_local -> scan_blocks -> place -> mlp -> aggregate.

constexpr int D = 128;
constexpr int SCAN_CHUNK = 1024;

typedef __attribute__((ext_vector_type(8))) short short8;
typedef __attribute__((ext_vector_type(4))) float f32x4;

__device__ __forceinline__ unsigned short f2bf(float x) {
    unsigned int u = __float_as_uint(x);
    u += 0x7fffu + ((u >> 16) & 1u);
    return (unsigned short)(u >> 16);
}
__device__ __forceinline__ float bflo(unsigned int u) { return __uint_as_float(u << 16); }
__device__ __forceinline__ float bfhi(unsigned int u) { return __uint_as_float(u & 0xffff0000u); }
__device__ __forceinline__ float fast_tanh(float x) {
    float e = exp2f(x * 2.885390081777927f);
    return fmaf(-2.0f, __builtin_amdgcn_rcpf(e + 1.0f), 1.0f);
}

// ---- K0: W transpose->bf16 (blocks 0..63) | zero count+selfc (rest) ----
__global__ __launch_bounds__(256) void k_prep_zero(const float* __restrict__ W1,
                                                   const float* __restrict__ W2,
                                                   unsigned short* __restrict__ Wt1,
                                                   unsigned short* __restrict__ Wt2,
                                                   int* __restrict__ zbase, int zv4) {
    int b = blockIdx.x;
    if (b < 64) {
        int t = b * 256 + threadIdx.x;  // t = k*D+n, coalesced read
        int k = t >> 7, nn = t & 127;
        Wt1[nn * D + k] = f2bf(W1[t]);
        Wt2[nn * D + k] = f2bf(W2[t]);
    } else {
        int i = (b - 64) * 256 + threadIdx.x;
        if (i < zv4) ((int4*)zbase)[i] = make_int4(0, 0, 0, 0);
    }
}

// ---- K1: per-src edge count (+ rare self-loop count) ----
__global__ __launch_bounds__(256) void k_count(const int* __restrict__ src,
                                               const int* __restrict__ dst,
                                               int* __restrict__ count,
                                               int* __restrict__ selfc, int E) {
    int e = blockIdx.x * 256 + threadIdx.x;
    if (e >= E) return;
    int s = src[e];
    atomicAdd(&count[s], 1);
    if (s == dst[e]) atomicAdd(&selfc[s], 1);
}

// ---- K2: local exclusive scan; degree; count->0 (cursor) ----
__global__ __launch_bounds__(256) void k_scan_local(int* __restrict__ count,
                                                    const int* __restrict__ selfc,
                                                    const int* __restrict__ indp,
                                                    float* __restrict__ degree,
                                                    int* __restrict__ row_ptr,
                                                    int* __restrict__ block_sums, int n) {
    __shared__ int s[256];
    const int t = threadIdx.x;
    const int base = blockIdx.x * SCAN_CHUNK + t * 4;
    const float mask = (indp[0] < 2) ? 1.0f : 0.0f;  // MASK = (1,1,0,0)
    int v[4];
#pragma unroll
    for (int j = 0; j < 4; ++j) {
        v[j] = 0;
        if (base + j < n) {
            int c = count[base + j];
            v[j] = c;
            degree[base + j] = (float)c + (mask - 1.0f) * (float)selfc[base + j];
            count[base + j] = 0;
        }
    }
    int sum4 = v[0] + v[1] + v[2] + v[3];
    s[t] = sum4;
    __syncthreads();
#pragma unroll
    for (int off = 1; off < 256; off <<= 1) {
        int x = (t >= off) ? s[t - off] : 0;
        __syncthreads();
        s[t] += x;
        __syncthreads();
    }
    int excl = s[t] - sum4;
    if (t == 255) block_sums[blockIdx.x] = s[255];
#pragma unroll
    for (int j = 0; j < 4; ++j) {
        if (base + j < n) row_ptr[base + j] = excl;
        excl += v[j];
    }
}

// ---- K3: exclusive-scan block sums (in place) ----
__global__ __launch_bounds__(128) void k_scan_blocks(int* __restrict__ block_sums, int nb) {
    __shared__ int s[128];
    const int t = threadIdx.x;
    int v = (t < nb) ? block_sums[t] : 0;
    s[t] = v;
    __syncthreads();
#pragma unroll
    for (int off = 1; off < 128; off <<= 1) {
        int x = (t >= off) ? s[t - off] : 0;
        __syncthreads();
        s[t] += x;
        __syncthreads();
    }
    if (t < nb) block_sums[t] = s[t] - v;
}

// ---- K4: place pairs[pos] = (dst, degree[dst]*W_edge[e]) in CSR-by-src order ----
__global__ __launch_bounds__(256) void k_place(const int* __restrict__ src,
                                               const int* __restrict__ dst,
                                               const float* __restrict__ W_edge,
                                               const float* __restrict__ degree,
                                               const int* __restrict__ row_ptr,
                                               const int* __restrict__ bsum,
                                               int* __restrict__ cursor,
                                               float2* __restrict__ pairs, int E) {
    int e = blockIdx.x * 256 + threadIdx.x;
    if (e >= E) return;
    int s = src[e];
    int d = dst[e];
    int pos = row_ptr[s] + bsum[s >> 10] + atomicAdd(&cursor[s], 1);
    float2 p;
    p.x = __int_as_float(d);
    p.y = degree[d] * W_edge[e];
    pairs[pos] = p;
}

// ---- K5: MLP, 128 rows/block, 4 waves x 32 rows, barrier-free, big VGPR budget ----
__global__ __launch_bounds__(256, 2) void k_mlp(const float* __restrict__ feat,
                                                const unsigned short* __restrict__ Wt1,
                                                const unsigned short* __restrict__ Wt2,
                                                const float* __restrict__ b1,
                                                const float* __restrict__ b2,
                                                unsigned short* __restrict__ hbf, int n) {
    __shared__ unsigned short sT[128 * D];  // 32 KB; each wave owns its 8 KB
    const int t = threadIdx.x;
    const int lane = t & 63;
    const int w = t >> 6;
    const int rl0 = w * 32;                    // wave's LDS row base
    const int row0 = blockIdx.x * 128 + rl0;   // wave's global row base
    const int rA = lane & 15;
    const int ks = (lane >> 4) * 8;

    // hoist biases (col = nf*16 + rA)
    float bias1[8], bias2[8];
#pragma unroll
    for (int nf = 0; nf < 8; ++nf) {
        bias1[nf] = b1[nf * 16 + rA];
        bias2[nf] = b2[nf * 16 + rA];
    }

    // hoist ALL feat loads (8 x float4 x 2 rf): one HBM latency for the wave
    float4 f[2][4][2];
#pragma unroll
    for (int rf = 0; rf < 2; ++rf) {
        int gr = row0 + rf * 16 + rA;
        bool ok = gr < n;
        const float* fp = &feat[(size_t)(ok ? gr : 0) * D + ks];
#pragma unroll
        for (int kc = 0; kc < 4; ++kc) {
            f[rf][kc][0] = ok ? *(const float4*)(fp + kc * 32) : make_float4(0.f, 0.f, 0.f, 0.f);
            f[rf][kc][1] = ok ? *(const float4*)(fp + kc * 32 + 4) : make_float4(0.f, 0.f, 0.f, 0.f);
        }
    }
    // convert to bf16 A-fragments
    short8 afrag[2][4];
#pragma unroll
    for (int rf = 0; rf < 2; ++rf)
#pragma unroll
        for (int kc = 0; kc < 4; ++kc) {
            float4 f0 = f[rf][kc][0], f1 = f[rf][kc][1];
            short8 a;
            a[0] = (short)f2bf(f0.x); a[1] = (short)f2bf(f0.y);
            a[2] = (short)f2bf(f0.z); a[3] = (short)f2bf(f0.w);
            a[4] = (short)f2bf(f1.x); a[5] = (short)f2bf(f1.y);
            a[6] = (short)f2bf(f1.z); a[7] = (short)f2bf(f1.w);
            afrag[rf][kc] = a;
        }

    f32x4 acc[2][8];
#pragma unroll
    for (int rf = 0; rf < 2; ++rf)
#pragma unroll
        for (int nf = 0; nf < 8; ++nf) acc[rf][nf] = (f32x4){0.f, 0.f, 0.f, 0.f};

    // GEMM1: B direct from Wt1 (L2-resident)
#pragma unroll
    for (int kc = 0; kc < 4; ++kc) {
#pragma unroll
        for (int nf = 0; nf < 8; ++nf) {
            short8 b = *(const short8*)&Wt1[(nf * 16 + rA) * D + kc * 32 + ks];
            acc[0][nf] = __builtin_amdgcn_mfma_f32_16x16x32_bf16(afrag[0][kc], b, acc[0][nf], 0, 0, 0);
            acc[1][nf] = __builtin_amdgcn_mfma_f32_16x16x32_bf16(afrag[1][kc], b, acc[1][nf], 0, 0, 0);
        }
    }

    // tanh -> own 32 LDS rows (swizzled); wave-local, no barrier
#pragma unroll
    for (int rf = 0; rf < 2; ++rf)
#pragma unroll
        for (int nf = 0; nf < 8; ++nf) {
            const int col = nf * 16 + rA;
#pragma unroll
            for (int i = 0; i < 4; ++i) {
                const int rl = rl0 + rf * 16 + (lane >> 4) * 4 + i;
                unsigned short hv = f2bf(fast_tanh(acc[rf][nf][i] + bias1[nf]));
                *(unsigned short*)((char*)sT + ((rl * 256 + col * 2) ^ ((rl & 7) << 4))) = hv;
            }
        }

#pragma unroll
    for (int rf = 0; rf < 2; ++rf)
#pragma unroll
        for (int nf = 0; nf < 8; ++nf) acc[rf][nf] = (f32x4){0.f, 0.f, 0.f, 0.f};

    // GEMM2: A from own LDS rows, B direct from Wt2
#pragma unroll
    for (int kc = 0; kc < 4; ++kc) {
        const int kb = (kc * 32 + ks) * 2;
        const int ra0 = rl0 + rA;
        const int ra1 = ra0 + 16;
        short8 a0 = *(short8*)((char*)sT + ((ra0 * 256 + kb) ^ ((ra0 & 7) << 4)));
        short8 a1 = *(short8*)((char*)sT + ((ra1 * 256 + kb) ^ ((ra1 & 7) << 4)));
#pragma unroll
        for (int nf = 0; nf < 8; ++nf) {
            short8 b = *(const short8*)&Wt2[(nf * 16 + rA) * D + kc * 32 + ks];
            acc[0][nf] = __builtin_amdgcn_mfma_f32_16x16x32_bf16(a0, b, acc[0][nf], 0, 0, 0);
            acc[1][nf] = __builtin_amdgcn_mfma_f32_16x16x32_bf16(a1, b, acc[1][nf], 0, 0, 0);
        }
    }

    // epilogue: +b2 -> bf16 -> own LDS rows
#pragma unroll
    for (int rf = 0; rf < 2; ++rf)
#pragma unroll
        for (int nf = 0; nf < 8; ++nf) {
            const int col = nf * 16 + rA;
#pragma unroll
            for (int i = 0; i < 4; ++i) {
                const int rl = rl0 + rf * 16 + (lane >> 4) * 4 + i;
                unsigned short hv = f2bf(acc[rf][nf][i] + bias2[nf]);
                *(unsigned short*)((char*)sT + ((rl * 256 + col * 2) ^ ((rl & 7) << 4))) = hv;
            }
        }

    // coalesced store of own 32 rows
    for (int c = lane; c < 512; c += 64) {
        int r = c >> 4, k0 = (c & 15) * 8;
        int gr = row0 + r;
        if (gr < n) {
            int rl = rl0 + r;
            short8 v = *(short8*)((char*)sT + ((rl * 256 + k0 * 2) ^ ((rl & 7) << 4)));
            *(short8*)&hbf[(size_t)gr * D + k0] = v;
        }
    }
}

// ---- K6: aggregate, 16 lanes/node; lane-parallel pairs + shfl broadcast ----
__global__ __launch_bounds__(256) void k_aggregate(const int* __restrict__ row_ptr,
                                                   const int* __restrict__ bsum,
                                                   const float2* __restrict__ pairs,
                                                   const unsigned short* __restrict__ hbf,
                                                   float* __restrict__ out, int n, int E) {
    long long tid = (long long)blockIdx.x * 256 + threadIdx.x;
    int node = (int)(tid >> 4);
    int li = (int)(tid & 15);
    int lane = threadIdx.x & 63;
    if (node >= n) return;
    int beg = row_ptr[node] + bsum[node >> 10];
    int end = (node + 1 == n) ? E : row_ptr[node + 1] + bsum[(node + 1) >> 10];

    float acc[8];
#pragma unroll
    for (int j = 0; j < 8; ++j) acc[j] = 0.f;
    float rsp = 0.f;
    const int gbase = lane & 48;

    for (int base = beg; base < end; base += 16) {
        int m = end - base;
        m = (m > 16) ? 16 : m;
        float2 p = make_float2(0.f, 0.f);
        if (li < m) p = pairs[base + li];
        rsp += p.y;
        int i = 0;
        for (; i + 1 < m; i += 2) {
            int d0 = __float_as_int(__shfl(p.x, gbase + i));
            float w0 = __shfl(p.y, gbase + i);
            int d1 = __float_as_int(__shfl(p.x, gbase + i + 1));
            float w1 = __shfl(p.y, gbase + i + 1);
            uint4 h0 = *(const uint4*)&hbf[(size_t)d0 * D + li * 8];
            uint4 h1 = *(const uint4*)&hbf[(size_t)d1 * D + li * 8];
            acc[0] = fmaf(w0, bflo(h0.x), acc[0]); acc[1] = fmaf(w0, bfhi(h0.x), acc[1]);
            acc[2] = fmaf(w0, bflo(h0.y), acc[2]); acc[3] = fmaf(w0, bfhi(h0.y), acc[3]);
            acc[4] = fmaf(w0, bflo(h0.z), acc[4]); acc[5] = fmaf(w0, bfhi(h0.z), acc[5]);
            acc[6] = fmaf(w0, bflo(h0.w), acc[6]); acc[7] = fmaf(w0, bfhi(h0.w), acc[7]);
            acc[0] = fmaf(w1, bflo(h1.x), acc[0]); acc[1] = fmaf(w1, bfhi(h1.x), acc[1]);
            acc[2] = fmaf(w1, bflo(h1.y), acc[2]); acc[3] = fmaf(w1, bfhi(h1.y), acc[3]);
            acc[4] = fmaf(w1, bflo(h1.z), acc[4]); acc[5] = fmaf(w1, bfhi(h1.z), acc[5]);
            acc[6] = fmaf(w1, bflo(h1.w), acc[6]); acc[7] = fmaf(w1, bfhi(h1.w), acc[7]);
        }
        if (i < m) {
            int d0 = __float_as_int(__shfl(p.x, gbase + i));
            float w0 = __shfl(p.y, gbase + i);
            uint4 h0 = *(const uint4*)&hbf[(size_t)d0 * D + li * 8];
            acc[0] = fmaf(w0, bflo(h0.x), acc[0]); acc[1] = fmaf(w0, bfhi(h0.x), acc[1]);
            acc[2] = fmaf(w0, bflo(h0.y), acc[2]); acc[3] = fmaf(w0, bfhi(h0.y), acc[3]);
            acc[4] = fmaf(w0, bflo(h0.z), acc[4]); acc[5] = fmaf(w0, bfhi(h0.z), acc[5]);
            acc[6] = fmaf(w0, bflo(h0.w), acc[6]); acc[7] = fmaf(w0, bfhi(h0.w), acc[7]);
        }
    }
    rsp += __shfl_xor(rsp, 1);
    rsp += __shfl_xor(rsp, 2);
    rsp += __shfl_xor(rsp, 4);
    rsp += __shfl_xor(rsp, 8);
    rsp = (rsp == 0.f) ? 1.f : rsp;
    float inv = 1.0f / rsp;
    float4 o0, o1;
    o0.x = acc[0] * inv; o0.y = acc[1] * inv; o0.z = acc[2] * inv; o0.w = acc[3] * inv;
    o1.x = acc[4] * inv; o1.y = acc[5] * inv; o1.z = acc[6] * inv; o1.w = acc[7] * inv;
    float* op = &out[(size_t)node * D + li * 8];
    *(float4*)op = o0;
    *(float4*)(op + 4) = o1;
}

extern "C" void kernel_launch(void* const* d_in, const int* in_sizes, int n_in,
                              void* d_out, int out_size, void* d_ws, size_t ws_size,
                              hipStream_t stream) {
    const float* feat   = (const float*)d_in[0];
    const float* W_edge = (const float*)d_in[1];
    const float* W1     = (const float*)d_in[2];
    const float* b1     = (const float*)d_in[3];
    const float* W2     = (const float*)d_in[4];
    const float* b2     = (const float*)d_in[5];
    const int* edge_src = (const int*)d_in[6];
    const int* edge_dst = (const int*)d_in[7];
    const int* indp     = (const int*)d_in[8];

    const int n = in_sizes[0] / D;   // 100000
    const int E = in_sizes[6];       // 600000
    const int nb = (n + SCAN_CHUNK - 1) / SCAN_CHUNK;  // 98

    // ws (16B-aligned front): Wt1 u16[D*D] | Wt2 u16[D*D] | degree f[n] | pairs f2[E] |
    //     hbf u16[n*D] | count i[n] | selfc i[n] | row_ptr i[n+1] | bsum i[128]
    char* ws = (char*)d_ws;
    unsigned short* Wt1 = (unsigned short*)ws;
    unsigned short* Wt2 = Wt1 + D * D;
    float* degree       = (float*)(Wt2 + D * D);
    float2* pairs       = (float2*)(degree + n);
    unsigned short* hbf = (unsigned short*)(pairs + E);
    int* count          = (int*)(hbf + (size_t)n * D);
    int* selfc          = count + n;
    int* row_ptr        = selfc + n;
    int* block_sums     = row_ptr + (n + 1);

    const int zv4 = (2 * n) / 4;
    const int zb = (zv4 + 255) / 256;            // 196
    k_prep_zero<<<64 + zb, 256, 0, stream>>>(W1, W2, Wt1, Wt2, count, zv4);

    const int eb = (E + 255) / 256;              // 2344
    k_count<<<eb, 256, 0, stream>>>(edge_src, edge_dst, count, selfc, E);
    k_scan_local<<<nb, 256, 0, stream>>>(count, selfc, indp, degree, row_ptr, block_sums, n);
    k_scan_blocks<<<1, 128, 0, stream>>>(block_sums, nb);
    k_place<<<eb, 256, 0, stream>>>(edge_src, edge_dst, W_edge, degree, row_ptr, block_sums,
                                    count, pairs, E);

    k_mlp<<<(n + 127) / 128, 256, 0, stream>>>(feat, Wt1, Wt2, b1, b2, hbf, n);

    long long athreads = (long long)n * 16;
    k_aggregate<<<(int)((athreads + 255) / 256), 256, 0, stream>>>(row_ptr, block_sums, pairs,
                                                                   hbf, (float*)d_out, n, E);
}

// Round 8
// 131.110 us; speedup vs baseline: 1.2884x; 1.1594x over previous
//
#include <hip/hip_runtime.h>

// MeanAggregator on MI355X.
// [Wprep(swizzled)|zero] -> count -> scan_local -> scan_blocks -> place -> mlp -> aggregate.

constexpr int D = 128;
constexpr int SCAN_CHUNK = 1024;

typedef __attribute__((ext_vector_type(8))) short short8;
typedef __attribute__((ext_vector_type(4))) float f32x4;
struct ushort8_s { unsigned short v[8]; };

__device__ __forceinline__ unsigned short f2bf(float x) {
    unsigned int u = __float_as_uint(x);
    u += 0x7fffu + ((u >> 16) & 1u);
    return (unsigned short)(u >> 16);
}
__device__ __forceinline__ float bflo(unsigned int u) { return __uint_as_float(u << 16); }
__device__ __forceinline__ float bfhi(unsigned int u) { return __uint_as_float(u & 0xffff0000u); }
__device__ __forceinline__ float fast_tanh(float x) {
    float e = exp2f(x * 2.885390081777927f);
    return fmaf(-2.0f, __builtin_amdgcn_rcpf(e + 1.0f), 1.0f);
}
// swizzled byte offset inside a [128 rows x 256 B] tile
__device__ __forceinline__ int swz(int row, int kbyte) {
    return (row * 256 + kbyte) ^ ((row & 7) << 4);
}

// ---- K0: W transpose->bf16 into PRE-SWIZZLED image (blocks 0..63) | zero (rest) ----
__global__ __launch_bounds__(256) void k_prep_zero(const float* __restrict__ W1,
                                                   const float* __restrict__ W2,
                                                   unsigned short* __restrict__ Wt1s,
                                                   unsigned short* __restrict__ Wt2s,
                                                   int* __restrict__ zbase, int zv4) {
    int b = blockIdx.x;
    if (b < 64) {
        int t = b * 256 + threadIdx.x;  // t = k*D + nn (coalesced read)
        int k = t >> 7, nn = t & 127;
        int si = swz(nn, k * 2) >> 1;   // u16 index in swizzled image
        Wt1s[si] = f2bf(W1[t]);
        Wt2s[si] = f2bf(W2[t]);
    } else {
        int i = (b - 64) * 256 + threadIdx.x;
        if (i < zv4) ((int4*)zbase)[i] = make_int4(0, 0, 0, 0);
    }
}

// ---- K1: per-src edge count (+ rare self-loop count) ----
__global__ __launch_bounds__(256) void k_count(const int* __restrict__ src,
                                               const int* __restrict__ dst,
                                               int* __restrict__ count,
                                               int* __restrict__ selfc, int E) {
    int e = blockIdx.x * 256 + threadIdx.x;
    if (e >= E) return;
    int s = src[e];
    atomicAdd(&count[s], 1);
    if (s == dst[e]) atomicAdd(&selfc[s], 1);
}

// ---- K2: local exclusive scan; degree; count->0 (cursor) ----
__global__ __launch_bounds__(256) void k_scan_local(int* __restrict__ count,
                                                    const int* __restrict__ selfc,
                                                    const int* __restrict__ indp,
                                                    float* __restrict__ degree,
                                                    int* __restrict__ row_ptr,
                                                    int* __restrict__ block_sums, int n) {
    __shared__ int s[256];
    const int t = threadIdx.x;
    const int base = blockIdx.x * SCAN_CHUNK + t * 4;
    const float mask = (indp[0] < 2) ? 1.0f : 0.0f;  // MASK = (1,1,0,0)
    int v[4];
#pragma unroll
    for (int j = 0; j < 4; ++j) {
        v[j] = 0;
        if (base + j < n) {
            int c = count[base + j];
            v[j] = c;
            degree[base + j] = (float)c + (mask - 1.0f) * (float)selfc[base + j];
            count[base + j] = 0;
        }
    }
    int sum4 = v[0] + v[1] + v[2] + v[3];
    s[t] = sum4;
    __syncthreads();
#pragma unroll
    for (int off = 1; off < 256; off <<= 1) {
        int x = (t >= off) ? s[t - off] : 0;
        __syncthreads();
        s[t] += x;
        __syncthreads();
    }
    int excl = s[t] - sum4;
    if (t == 255) block_sums[blockIdx.x] = s[255];
#pragma unroll
    for (int j = 0; j < 4; ++j) {
        if (base + j < n) row_ptr[base + j] = excl;
        excl += v[j];
    }
}

// ---- K3: exclusive-scan block sums (in place) ----
__global__ __launch_bounds__(128) void k_scan_blocks(int* __restrict__ block_sums, int nb) {
    __shared__ int s[128];
    const int t = threadIdx.x;
    int v = (t < nb) ? block_sums[t] : 0;
    s[t] = v;
    __syncthreads();
#pragma unroll
    for (int off = 1; off < 128; off <<= 1) {
        int x = (t >= off) ? s[t - off] : 0;
        __syncthreads();
        s[t] += x;
        __syncthreads();
    }
    if (t < nb) block_sums[t] = s[t] - v;
}

// ---- K4: place pairs[pos] = (dst, degree[dst]*W_edge[e]) in CSR-by-src order ----
__global__ __launch_bounds__(256) void k_place(const int* __restrict__ src,
                                               const int* __restrict__ dst,
                                               const float* __restrict__ W_edge,
                                               const float* __restrict__ degree,
                                               const int* __restrict__ row_ptr,
                                               const int* __restrict__ bsum,
                                               int* __restrict__ cursor,
                                               float2* __restrict__ pairs, int E) {
    int e = blockIdx.x * 256 + threadIdx.x;
    if (e >= E) return;
    int s = src[e];
    int d = dst[e];
    int pos = row_ptr[s] + bsum[s >> 10] + atomicAdd(&cursor[s], 1);
    float2 p;
    p.x = __int_as_float(d);
    p.y = degree[d] * W_edge[e];
    pairs[pos] = p;
}

// ---- K5: MLP, 128 rows/block, 4 waves x 32 rows; W staged once in LDS ----
// LDS: sW1 (32KB, reused as tanh/output tile sT) + sW2 (32KB) = 64KB -> 2 blocks/CU.
__global__ __launch_bounds__(256) void k_mlp(const float* __restrict__ feat,
                                             const unsigned short* __restrict__ Wt1s,
                                             const unsigned short* __restrict__ Wt2s,
                                             const float* __restrict__ b1,
                                             const float* __restrict__ b2,
                                             unsigned short* __restrict__ hbf, int n) {
    __shared__ unsigned short sW1[128 * D];  // swizzled Wt1; later sT
    __shared__ unsigned short sW2[128 * D];  // swizzled Wt2
    const int t = threadIdx.x;
    const int lane = t & 63;
    const int w = t >> 6;
    const int rl0 = w * 32;                    // wave's rows in sT
    const int row0 = blockIdx.x * 128 + rl0;   // wave's global rows
    const int rA = lane & 15;
    const int ks = (lane >> 4) * 8;

    // 1) issue feat loads first (HBM latency hides under W staging)
    float4 f[2][4][2];
#pragma unroll
    for (int rf = 0; rf < 2; ++rf) {
        int gr = row0 + rf * 16 + rA;
        bool ok = gr < n;
        const float* fp = &feat[(size_t)(ok ? gr : 0) * D + ks];
#pragma unroll
        for (int kc = 0; kc < 4; ++kc) {
            f[rf][kc][0] = ok ? *(const float4*)(fp + kc * 32) : make_float4(0.f, 0.f, 0.f, 0.f);
            f[rf][kc][1] = ok ? *(const float4*)(fp + kc * 32 + 4) : make_float4(0.f, 0.f, 0.f, 0.f);
        }
    }

    // 2) stage swizzled W images linearly into LDS (8 x 16B per thread per buffer)
    {
        const ushort8_s* g1 = (const ushort8_s*)Wt1s;
        const ushort8_s* g2 = (const ushort8_s*)Wt2s;
        ushort8_s* l1 = (ushort8_s*)sW1;
        ushort8_s* l2 = (ushort8_s*)sW2;
#pragma unroll
        for (int j = 0; j < 8; ++j) {
            int c = t + j * 256;
            l1[c] = g1[c];
            l2[c] = g2[c];
        }
    }

    // biases (col = nf*16 + rA)
    float bias1[8], bias2[8];
#pragma unroll
    for (int nf = 0; nf < 8; ++nf) {
        bias1[nf] = b1[nf * 16 + rA];
        bias2[nf] = b2[nf * 16 + rA];
    }

    // convert A to bf16 fragments
    short8 afrag[2][4];
#pragma unroll
    for (int rf = 0; rf < 2; ++rf)
#pragma unroll
        for (int kc = 0; kc < 4; ++kc) {
            float4 f0 = f[rf][kc][0], f1 = f[rf][kc][1];
            short8 a;
            a[0] = (short)f2bf(f0.x); a[1] = (short)f2bf(f0.y);
            a[2] = (short)f2bf(f0.z); a[3] = (short)f2bf(f0.w);
            a[4] = (short)f2bf(f1.x); a[5] = (short)f2bf(f1.y);
            a[6] = (short)f2bf(f1.z); a[7] = (short)f2bf(f1.w);
            afrag[rf][kc] = a;
        }

    __syncthreads();  // W staged

    f32x4 acc[2][8];
#pragma unroll
    for (int rf = 0; rf < 2; ++rf)
#pragma unroll
        for (int nf = 0; nf < 8; ++nf) acc[rf][nf] = (f32x4){0.f, 0.f, 0.f, 0.f};

    // GEMM1: B from sW1 (swizzled ds_read_b128)
#pragma unroll
    for (int kc = 0; kc < 4; ++kc) {
        const int kb = (kc * 32 + ks) * 2;
#pragma unroll
        for (int nf = 0; nf < 8; ++nf) {
            const int rb = nf * 16 + rA;
            short8 b = *(short8*)((char*)sW1 + swz(rb, kb));
            acc[0][nf] = __builtin_amdgcn_mfma_f32_16x16x32_bf16(afrag[0][kc], b, acc[0][nf], 0, 0, 0);
            acc[1][nf] = __builtin_amdgcn_mfma_f32_16x16x32_bf16(afrag[1][kc], b, acc[1][nf], 0, 0, 0);
        }
    }

    __syncthreads();  // everyone done reading sW1 before it becomes sT

    // tanh -> own 32 rows of sT (= sW1 space); wave-local from here on
#pragma unroll
    for (int rf = 0; rf < 2; ++rf)
#pragma unroll
        for (int nf = 0; nf < 8; ++nf) {
            const int col = nf * 16 + rA;
#pragma unroll
            for (int i = 0; i < 4; ++i) {
                const int rl = rl0 + rf * 16 + (lane >> 4) * 4 + i;
                unsigned short hv = f2bf(fast_tanh(acc[rf][nf][i] + bias1[nf]));
                *(unsigned short*)((char*)sW1 + swz(rl, col * 2)) = hv;
            }
        }

#pragma unroll
    for (int rf = 0; rf < 2; ++rf)
#pragma unroll
        for (int nf = 0; nf < 8; ++nf) acc[rf][nf] = (f32x4){0.f, 0.f, 0.f, 0.f};

    // GEMM2: A from own sT rows, B from sW2
#pragma unroll
    for (int kc = 0; kc < 4; ++kc) {
        const int kb = (kc * 32 + ks) * 2;
        const int ra0 = rl0 + rA;
        const int ra1 = ra0 + 16;
        short8 a0 = *(short8*)((char*)sW1 + swz(ra0, kb));
        short8 a1 = *(short8*)((char*)sW1 + swz(ra1, kb));
#pragma unroll
        for (int nf = 0; nf < 8; ++nf) {
            const int rb = nf * 16 + rA;
            short8 b = *(short8*)((char*)sW2 + swz(rb, kb));
            acc[0][nf] = __builtin_amdgcn_mfma_f32_16x16x32_bf16(a0, b, acc[0][nf], 0, 0, 0);
            acc[1][nf] = __builtin_amdgcn_mfma_f32_16x16x32_bf16(a1, b, acc[1][nf], 0, 0, 0);
        }
    }

    // epilogue: +b2 -> bf16 -> own sT rows (own GEMM2 reads already consumed)
#pragma unroll
    for (int rf = 0; rf < 2; ++rf)
#pragma unroll
        for (int nf = 0; nf < 8; ++nf) {
            const int col = nf * 16 + rA;
#pragma unroll
            for (int i = 0; i < 4; ++i) {
                const int rl = rl0 + rf * 16 + (lane >> 4) * 4 + i;
                unsigned short hv = f2bf(acc[rf][nf][i] + bias2[nf]);
                *(unsigned short*)((char*)sW1 + swz(rl, col * 2)) = hv;
            }
        }

    // coalesced store of own 32 rows
    for (int c = lane; c < 512; c += 64) {
        int r = c >> 4, k0 = (c & 15) * 8;
        int gr = row0 + r;
        if (gr < n) {
            int rl = rl0 + r;
            short8 v = *(short8*)((char*)sW1 + swz(rl, k0 * 2));
            *(short8*)&hbf[(size_t)gr * D + k0] = v;
        }
    }
}

// ---- K6: aggregate, 16 lanes/node; lane-parallel pairs + shfl broadcast ----
__global__ __launch_bounds__(256) void k_aggregate(const int* __restrict__ row_ptr,
                                                   const int* __restrict__ bsum,
                                                   const float2* __restrict__ pairs,
                                                   const unsigned short* __restrict__ hbf,
                                                   float* __restrict__ out, int n, int E) {
    long long tid = (long long)blockIdx.x * 256 + threadIdx.x;
    int node = (int)(tid >> 4);
    int li = (int)(tid & 15);
    int lane = threadIdx.x & 63;
    if (node >= n) return;
    int beg = row_ptr[node] + bsum[node >> 10];
    int end = (node + 1 == n) ? E : row_ptr[node + 1] + bsum[(node + 1) >> 10];

    float acc[8];
#pragma unroll
    for (int j = 0; j < 8; ++j) acc[j] = 0.f;
    float rsp = 0.f;
    const int gbase = lane & 48;

    for (int base = beg; base < end; base += 16) {
        int m = end - base;
        m = (m > 16) ? 16 : m;
        float2 p = make_float2(0.f, 0.f);
        if (li < m) p = pairs[base + li];
        rsp += p.y;
        int i = 0;
        for (; i + 1 < m; i += 2) {
            int d0 = __float_as_int(__shfl(p.x, gbase + i));
            float w0 = __shfl(p.y, gbase + i);
            int d1 = __float_as_int(__shfl(p.x, gbase + i + 1));
            float w1 = __shfl(p.y, gbase + i + 1);
            uint4 h0 = *(const uint4*)&hbf[(size_t)d0 * D + li * 8];
            uint4 h1 = *(const uint4*)&hbf[(size_t)d1 * D + li * 8];
            acc[0] = fmaf(w0, bflo(h0.x), acc[0]); acc[1] = fmaf(w0, bfhi(h0.x), acc[1]);
            acc[2] = fmaf(w0, bflo(h0.y), acc[2]); acc[3] = fmaf(w0, bfhi(h0.y), acc[3]);
            acc[4] = fmaf(w0, bflo(h0.z), acc[4]); acc[5] = fmaf(w0, bfhi(h0.z), acc[5]);
            acc[6] = fmaf(w0, bflo(h0.w), acc[6]); acc[7] = fmaf(w0, bfhi(h0.w), acc[7]);
            acc[0] = fmaf(w1, bflo(h1.x), acc[0]); acc[1] = fmaf(w1, bfhi(h1.x), acc[1]);
            acc[2] = fmaf(w1, bflo(h1.y), acc[2]); acc[3] = fmaf(w1, bfhi(h1.y), acc[3]);
            acc[4] = fmaf(w1, bflo(h1.z), acc[4]); acc[5] = fmaf(w1, bfhi(h1.z), acc[5]);
            acc[6] = fmaf(w1, bflo(h1.w), acc[6]); acc[7] = fmaf(w1, bfhi(h1.w), acc[7]);
        }
        if (i < m) {
            int d0 = __float_as_int(__shfl(p.x, gbase + i));
            float w0 = __shfl(p.y, gbase + i);
            uint4 h0 = *(const uint4*)&hbf[(size_t)d0 * D + li * 8];
            acc[0] = fmaf(w0, bflo(h0.x), acc[0]); acc[1] = fmaf(w0, bfhi(h0.x), acc[1]);
            acc[2] = fmaf(w0, bflo(h0.y), acc[2]); acc[3] = fmaf(w0, bfhi(h0.y), acc[3]);
            acc[4] = fmaf(w0, bflo(h0.z), acc[4]); acc[5] = fmaf(w0, bfhi(h0.z), acc[5]);
            acc[6] = fmaf(w0, bflo(h0.w), acc[6]); acc[7] = fmaf(w0, bfhi(h0.w), acc[7]);
        }
    }
    rsp += __shfl_xor(rsp, 1);
    rsp += __shfl_xor(rsp, 2);
    rsp += __shfl_xor(rsp, 4);
    rsp += __shfl_xor(rsp, 8);
    rsp = (rsp == 0.f) ? 1.f : rsp;
    float inv = 1.0f / rsp;
    float4 o0, o1;
    o0.x = acc[0] * inv; o0.y = acc[1] * inv; o0.z = acc[2] * inv; o0.w = acc[3] * inv;
    o1.x = acc[4] * inv; o1.y = acc[5] * inv; o1.z = acc[6] * inv; o1.w = acc[7] * inv;
    float* op = &out[(size_t)node * D + li * 8];
    *(float4*)op = o0;
    *(float4*)(op + 4) = o1;
}

extern "C" void kernel_launch(void* const* d_in, const int* in_sizes, int n_in,
                              void* d_out, int out_size, void* d_ws, size_t ws_size,
                              hipStream_t stream) {
    const float* feat   = (const float*)d_in[0];
    const float* W_edge = (const float*)d_in[1];
    const float* W1     = (const float*)d_in[2];
    const float* b1     = (const float*)d_in[3];
    const float* W2     = (const float*)d_in[4];
    const float* b2     = (const float*)d_in[5];
    const int* edge_src = (const int*)d_in[6];
    const int* edge_dst = (const int*)d_in[7];
    const int* indp     = (const int*)d_in[8];

    const int n = in_sizes[0] / D;   // 100000
    const int E = in_sizes[6];       // 600000
    const int nb = (n + SCAN_CHUNK - 1) / SCAN_CHUNK;  // 98

    // ws (16B-aligned front): Wt1s u16[D*D] | Wt2s u16[D*D] | degree f[n] | pairs f2[E] |
    //     hbf u16[n*D] | count i[n] | selfc i[n] | row_ptr i[n+1] | bsum i[128]
    char* ws = (char*)d_ws;
    unsigned short* Wt1s = (unsigned short*)ws;
    unsigned short* Wt2s = Wt1s + D * D;
    float* degree       = (float*)(Wt2s + D * D);
    float2* pairs       = (float2*)(degree + n);
    unsigned short* hbf = (unsigned short*)(pairs + E);
    int* count          = (int*)(hbf + (size_t)n * D);
    int* selfc          = count + n;
    int* row_ptr        = selfc + n;
    int* block_sums     = row_ptr + (n + 1);

    const int zv4 = (2 * n) / 4;
    const int zb = (zv4 + 255) / 256;            // 196
    k_prep_zero<<<64 + zb, 256, 0, stream>>>(W1, W2, Wt1s, Wt2s, count, zv4);

    const int eb = (E + 255) / 256;              // 2344
    k_count<<<eb, 256, 0, stream>>>(edge_src, edge_dst, count, selfc, E);
    k_scan_local<<<nb, 256, 0, stream>>>(count, selfc, indp, degree, row_ptr, block_sums, n);
    k_scan_blocks<<<1, 128, 0, stream>>>(block_sums, nb);
    k_place<<<eb, 256, 0, stream>>>(edge_src, edge_dst, W_edge, degree, row_ptr, block_sums,
                                    count, pairs, E);

    k_mlp<<<(n + 127) / 128, 256, 0, stream>>>(feat, Wt1s, Wt2s, b1, b2, hbf, n);

    long long athreads = (long long)n * 16;
    k_aggregate<<<(int)((athreads + 255) / 256), 256, 0, stream>>>(row_ptr, block_sums, pairs,
                                                                   hbf, (float*)d_out, n, E);
}

// Round 9
// 116.278 us; speedup vs baseline: 1.4528x; 1.1276x over previous
//
#include <hip/hip_runtime.h>

// MeanAggregator on MI355X.
// memset -> [Wprep|count] -> scan_local -> scan_blocks -> [mlp|place] -> aggregate.

constexpr int D = 128;
constexpr int SCAN_CHUNK = 1024;

typedef __attribute__((ext_vector_type(8))) short short8;
typedef __attribute__((ext_vector_type(4))) float f32x4;
struct ushort8_s { unsigned short v[8]; };

__device__ __forceinline__ unsigned short f2bf(float x) {
    unsigned int u = __float_as_uint(x);
    u += 0x7fffu + ((u >> 16) & 1u);
    return (unsigned short)(u >> 16);
}
__device__ __forceinline__ float bflo(unsigned int u) { return __uint_as_float(u << 16); }
__device__ __forceinline__ float bfhi(unsigned int u) { return __uint_as_float(u & 0xffff0000u); }
__device__ __forceinline__ float fast_tanh(float x) {
    float e = exp2f(x * 2.885390081777927f);
    return fmaf(-2.0f, __builtin_amdgcn_rcpf(e + 1.0f), 1.0f);
}
// swizzled byte offset inside a [128 rows x 256 B] tile
__device__ __forceinline__ int swz(int row, int kbyte) {
    return (row * 256 + kbyte) ^ ((row & 7) << 4);
}

// ---- K0: W transpose->bf16 into PRE-SWIZZLED image (blocks 0..63) | count (rest) ----
__global__ __launch_bounds__(256) void k_prep_count(const float* __restrict__ W1,
                                                    const float* __restrict__ W2,
                                                    unsigned short* __restrict__ Wt1s,
                                                    unsigned short* __restrict__ Wt2s,
                                                    const int* __restrict__ src,
                                                    const int* __restrict__ dst,
                                                    int* __restrict__ count,
                                                    int* __restrict__ selfc, int E) {
    int b = blockIdx.x;
    if (b < 64) {
        int t = b * 256 + threadIdx.x;  // t = k*D + nn (coalesced read)
        int k = t >> 7, nn = t & 127;
        int si = swz(nn, k * 2) >> 1;   // u16 index in swizzled image
        Wt1s[si] = f2bf(W1[t]);
        Wt2s[si] = f2bf(W2[t]);
    } else {
        int e = (b - 64) * 256 + threadIdx.x;
        if (e < E) {
            int s = src[e];
            atomicAdd(&count[s], 1);
            if (s == dst[e]) atomicAdd(&selfc[s], 1);
        }
    }
}

// ---- K1: local exclusive scan; degree; count->0 (cursor) ----
__global__ __launch_bounds__(256) void k_scan_local(int* __restrict__ count,
                                                    const int* __restrict__ selfc,
                                                    const int* __restrict__ indp,
                                                    float* __restrict__ degree,
                                                    int* __restrict__ row_ptr,
                                                    int* __restrict__ block_sums, int n) {
    __shared__ int s[256];
    const int t = threadIdx.x;
    const int base = blockIdx.x * SCAN_CHUNK + t * 4;
    const float mask = (indp[0] < 2) ? 1.0f : 0.0f;  // MASK = (1,1,0,0)
    int v[4];
#pragma unroll
    for (int j = 0; j < 4; ++j) {
        v[j] = 0;
        if (base + j < n) {
            int c = count[base + j];
            v[j] = c;
            degree[base + j] = (float)c + (mask - 1.0f) * (float)selfc[base + j];
            count[base + j] = 0;
        }
    }
    int sum4 = v[0] + v[1] + v[2] + v[3];
    s[t] = sum4;
    __syncthreads();
#pragma unroll
    for (int off = 1; off < 256; off <<= 1) {
        int x = (t >= off) ? s[t - off] : 0;
        __syncthreads();
        s[t] += x;
        __syncthreads();
    }
    int excl = s[t] - sum4;
    if (t == 255) block_sums[blockIdx.x] = s[255];
#pragma unroll
    for (int j = 0; j < 4; ++j) {
        if (base + j < n) row_ptr[base + j] = excl;
        excl += v[j];
    }
}

// ---- K2: exclusive-scan block sums (in place) ----
__global__ __launch_bounds__(128) void k_scan_blocks(int* __restrict__ block_sums, int nb) {
    __shared__ int s[128];
    const int t = threadIdx.x;
    int v = (t < nb) ? block_sums[t] : 0;
    s[t] = v;
    __syncthreads();
#pragma unroll
    for (int off = 1; off < 128; off <<= 1) {
        int x = (t >= off) ? s[t - off] : 0;
        __syncthreads();
        s[t] += x;
        __syncthreads();
    }
    if (t < nb) block_sums[t] = s[t] - v;
}

// ---- K3: fused MLP (blocks < nm) | place (blocks >= nm) ----
// MLP: 128 rows/block, 4 waves x 32 rows; W staged once in LDS (sW1 reused as sT).
__global__ __launch_bounds__(256) void k_mlp_place(
        const float* __restrict__ feat,
        const unsigned short* __restrict__ Wt1s,
        const unsigned short* __restrict__ Wt2s,
        const float* __restrict__ b1, const float* __restrict__ b2,
        unsigned short* __restrict__ hbf, int n, int nm,
        const int* __restrict__ src, const int* __restrict__ dst,
        const float* __restrict__ W_edge, const float* __restrict__ degree,
        const int* __restrict__ row_ptr, const int* __restrict__ bsum,
        int* __restrict__ cursor, float2* __restrict__ pairs, int E) {
    __shared__ unsigned short sW1[128 * D];  // swizzled Wt1; later sT
    __shared__ unsigned short sW2[128 * D];  // swizzled Wt2
    if (blockIdx.x >= nm) {
        int e = (blockIdx.x - nm) * 256 + threadIdx.x;
        if (e < E) {
            int s = src[e];
            int d = dst[e];
            int pos = row_ptr[s] + bsum[s >> 10] + atomicAdd(&cursor[s], 1);
            float2 p;
            p.x = __int_as_float(d);
            p.y = degree[d] * W_edge[e];
            pairs[pos] = p;
        }
        return;
    }
    const int t = threadIdx.x;
    const int lane = t & 63;
    const int w = t >> 6;
    const int rl0 = w * 32;                    // wave's rows in sT
    const int row0 = blockIdx.x * 128 + rl0;   // wave's global rows
    const int rA = lane & 15;
    const int ks = (lane >> 4) * 8;

    // 1) issue feat loads first (HBM latency hides under W staging)
    float4 f[2][4][2];
#pragma unroll
    for (int rf = 0; rf < 2; ++rf) {
        int gr = row0 + rf * 16 + rA;
        bool ok = gr < n;
        const float* fp = &feat[(size_t)(ok ? gr : 0) * D + ks];
#pragma unroll
        for (int kc = 0; kc < 4; ++kc) {
            f[rf][kc][0] = ok ? *(const float4*)(fp + kc * 32) : make_float4(0.f, 0.f, 0.f, 0.f);
            f[rf][kc][1] = ok ? *(const float4*)(fp + kc * 32 + 4) : make_float4(0.f, 0.f, 0.f, 0.f);
        }
    }

    // 2) stage swizzled W images linearly into LDS
    {
        const ushort8_s* g1 = (const ushort8_s*)Wt1s;
        const ushort8_s* g2 = (const ushort8_s*)Wt2s;
        ushort8_s* l1 = (ushort8_s*)sW1;
        ushort8_s* l2 = (ushort8_s*)sW2;
#pragma unroll
        for (int j = 0; j < 8; ++j) {
            int c = t + j * 256;
            l1[c] = g1[c];
            l2[c] = g2[c];
        }
    }

    float bias1[8], bias2[8];
#pragma unroll
    for (int nf = 0; nf < 8; ++nf) {
        bias1[nf] = b1[nf * 16 + rA];
        bias2[nf] = b2[nf * 16 + rA];
    }

    short8 afrag[2][4];
#pragma unroll
    for (int rf = 0; rf < 2; ++rf)
#pragma unroll
        for (int kc = 0; kc < 4; ++kc) {
            float4 f0 = f[rf][kc][0], f1 = f[rf][kc][1];
            short8 a;
            a[0] = (short)f2bf(f0.x); a[1] = (short)f2bf(f0.y);
            a[2] = (short)f2bf(f0.z); a[3] = (short)f2bf(f0.w);
            a[4] = (short)f2bf(f1.x); a[5] = (short)f2bf(f1.y);
            a[6] = (short)f2bf(f1.z); a[7] = (short)f2bf(f1.w);
            afrag[rf][kc] = a;
        }

    __syncthreads();  // W staged

    f32x4 acc[2][8];
#pragma unroll
    for (int rf = 0; rf < 2; ++rf)
#pragma unroll
        for (int nf = 0; nf < 8; ++nf) acc[rf][nf] = (f32x4){0.f, 0.f, 0.f, 0.f};

    // GEMM1: B from sW1
#pragma unroll
    for (int kc = 0; kc < 4; ++kc) {
        const int kb = (kc * 32 + ks) * 2;
#pragma unroll
        for (int nf = 0; nf < 8; ++nf) {
            const int rb = nf * 16 + rA;
            short8 b = *(short8*)((char*)sW1 + swz(rb, kb));
            acc[0][nf] = __builtin_amdgcn_mfma_f32_16x16x32_bf16(afrag[0][kc], b, acc[0][nf], 0, 0, 0);
            acc[1][nf] = __builtin_amdgcn_mfma_f32_16x16x32_bf16(afrag[1][kc], b, acc[1][nf], 0, 0, 0);
        }
    }

    __syncthreads();  // all B-reads of sW1 done before it becomes sT

    // tanh -> own 32 rows of sT (= sW1 space); wave-local from here on
#pragma unroll
    for (int rf = 0; rf < 2; ++rf)
#pragma unroll
        for (int nf = 0; nf < 8; ++nf) {
            const int col = nf * 16 + rA;
#pragma unroll
            for (int i = 0; i < 4; ++i) {
                const int rl = rl0 + rf * 16 + (lane >> 4) * 4 + i;
                unsigned short hv = f2bf(fast_tanh(acc[rf][nf][i] + bias1[nf]));
                *(unsigned short*)((char*)sW1 + swz(rl, col * 2)) = hv;
            }
        }

#pragma unroll
    for (int rf = 0; rf < 2; ++rf)
#pragma unroll
        for (int nf = 0; nf < 8; ++nf) acc[rf][nf] = (f32x4){0.f, 0.f, 0.f, 0.f};

    // GEMM2: A from own sT rows, B from sW2
#pragma unroll
    for (int kc = 0; kc < 4; ++kc) {
        const int kb = (kc * 32 + ks) * 2;
        const int ra0 = rl0 + rA;
        const int ra1 = ra0 + 16;
        short8 a0 = *(short8*)((char*)sW1 + swz(ra0, kb));
        short8 a1 = *(short8*)((char*)sW1 + swz(ra1, kb));
#pragma unroll
        for (int nf = 0; nf < 8; ++nf) {
            const int rb = nf * 16 + rA;
            short8 b = *(short8*)((char*)sW2 + swz(rb, kb));
            acc[0][nf] = __builtin_amdgcn_mfma_f32_16x16x32_bf16(a0, b, acc[0][nf], 0, 0, 0);
            acc[1][nf] = __builtin_amdgcn_mfma_f32_16x16x32_bf16(a1, b, acc[1][nf], 0, 0, 0);
        }
    }

    // epilogue: +b2 -> bf16 -> own sT rows
#pragma unroll
    for (int rf = 0; rf < 2; ++rf)
#pragma unroll
        for (int nf = 0; nf < 8; ++nf) {
            const int col = nf * 16 + rA;
#pragma unroll
            for (int i = 0; i < 4; ++i) {
                const int rl = rl0 + rf * 16 + (lane >> 4) * 4 + i;
                unsigned short hv = f2bf(acc[rf][nf][i] + bias2[nf]);
                *(unsigned short*)((char*)sW1 + swz(rl, col * 2)) = hv;
            }
        }

    // coalesced store of own 32 rows
    for (int c = lane; c < 512; c += 64) {
        int r = c >> 4, k0 = (c & 15) * 8;
        int gr = row0 + r;
        if (gr < n) {
            int rl = rl0 + r;
            short8 v = *(short8*)((char*)sW1 + swz(rl, k0 * 2));
            *(short8*)&hbf[(size_t)gr * D + k0] = v;
        }
    }
}

// ---- K4: aggregate, 16 lanes/node; lane-parallel pairs + shfl; 4-deep unroll ----
__global__ __launch_bounds__(256) void k_aggregate(const int* __restrict__ row_ptr,
                                                   const int* __restrict__ bsum,
                                                   const float2* __restrict__ pairs,
                                                   const unsigned short* __restrict__ hbf,
                                                   float* __restrict__ out, int n, int E) {
    long long tid = (long long)blockIdx.x * 256 + threadIdx.x;
    int node = (int)(tid >> 4);
    int li = (int)(tid & 15);
    int lane = threadIdx.x & 63;
    if (node >= n) return;
    int beg = row_ptr[node] + bsum[node >> 10];
    int end = (node + 1 == n) ? E : row_ptr[node + 1] + bsum[(node + 1) >> 10];

    float acc[8];
#pragma unroll
    for (int j = 0; j < 8; ++j) acc[j] = 0.f;
    float rsp = 0.f;
    const int gbase = lane & 48;

    auto fma8 = [&](float w, uint4 h) {
        acc[0] = fmaf(w, bflo(h.x), acc[0]); acc[1] = fmaf(w, bfhi(h.x), acc[1]);
        acc[2] = fmaf(w, bflo(h.y), acc[2]); acc[3] = fmaf(w, bfhi(h.y), acc[3]);
        acc[4] = fmaf(w, bflo(h.z), acc[4]); acc[5] = fmaf(w, bfhi(h.z), acc[5]);
        acc[6] = fmaf(w, bflo(h.w), acc[6]); acc[7] = fmaf(w, bfhi(h.w), acc[7]);
    };

    for (int base = beg; base < end; base += 16) {
        int m = end - base;
        m = (m > 16) ? 16 : m;
        float2 p = make_float2(0.f, 0.f);
        if (li < m) p = pairs[base + li];
        rsp += p.y;
        int i = 0;
        for (; i + 3 < m; i += 4) {
            int d0 = __float_as_int(__shfl(p.x, gbase + i));
            float w0 = __shfl(p.y, gbase + i);
            int d1 = __float_as_int(__shfl(p.x, gbase + i + 1));
            float w1 = __shfl(p.y, gbase + i + 1);
            int d2 = __float_as_int(__shfl(p.x, gbase + i + 2));
            float w2 = __shfl(p.y, gbase + i + 2);
            int d3 = __float_as_int(__shfl(p.x, gbase + i + 3));
            float w3 = __shfl(p.y, gbase + i + 3);
            uint4 h0 = *(const uint4*)&hbf[(size_t)d0 * D + li * 8];
            uint4 h1 = *(const uint4*)&hbf[(size_t)d1 * D + li * 8];
            uint4 h2 = *(const uint4*)&hbf[(size_t)d2 * D + li * 8];
            uint4 h3 = *(const uint4*)&hbf[(size_t)d3 * D + li * 8];
            fma8(w0, h0); fma8(w1, h1); fma8(w2, h2); fma8(w3, h3);
        }
        for (; i + 1 < m; i += 2) {
            int d0 = __float_as_int(__shfl(p.x, gbase + i));
            float w0 = __shfl(p.y, gbase + i);
            int d1 = __float_as_int(__shfl(p.x, gbase + i + 1));
            float w1 = __shfl(p.y, gbase + i + 1);
            uint4 h0 = *(const uint4*)&hbf[(size_t)d0 * D + li * 8];
            uint4 h1 = *(const uint4*)&hbf[(size_t)d1 * D + li * 8];
            fma8(w0, h0); fma8(w1, h1);
        }
        if (i < m) {
            int d0 = __float_as_int(__shfl(p.x, gbase + i));
            float w0 = __shfl(p.y, gbase + i);
            uint4 h0 = *(const uint4*)&hbf[(size_t)d0 * D + li * 8];
            fma8(w0, h0);
        }
    }
    rsp += __shfl_xor(rsp, 1);
    rsp += __shfl_xor(rsp, 2);
    rsp += __shfl_xor(rsp, 4);
    rsp += __shfl_xor(rsp, 8);
    rsp = (rsp == 0.f) ? 1.f : rsp;
    float inv = 1.0f / rsp;
    float4 o0, o1;
    o0.x = acc[0] * inv; o0.y = acc[1] * inv; o0.z = acc[2] * inv; o0.w = acc[3] * inv;
    o1.x = acc[4] * inv; o1.y = acc[5] * inv; o1.z = acc[6] * inv; o1.w = acc[7] * inv;
    float* op = &out[(size_t)node * D + li * 8];
    *(float4*)op = o0;
    *(float4*)(op + 4) = o1;
}

extern "C" void kernel_launch(void* const* d_in, const int* in_sizes, int n_in,
                              void* d_out, int out_size, void* d_ws, size_t ws_size,
                              hipStream_t stream) {
    const float* feat   = (const float*)d_in[0];
    const float* W_edge = (const float*)d_in[1];
    const float* W1     = (const float*)d_in[2];
    const float* b1     = (const float*)d_in[3];
    const float* W2     = (const float*)d_in[4];
    const float* b2     = (const float*)d_in[5];
    const int* edge_src = (const int*)d_in[6];
    const int* edge_dst = (const int*)d_in[7];
    const int* indp     = (const int*)d_in[8];

    const int n = in_sizes[0] / D;   // 100000
    const int E = in_sizes[6];       // 600000
    const int nb = (n + SCAN_CHUNK - 1) / SCAN_CHUNK;  // 98

    // ws (16B-aligned front): Wt1s u16[D*D] | Wt2s u16[D*D] | degree f[n] | pairs f2[E] |
    //     hbf u16[n*D] | count i[n] | selfc i[n] | row_ptr i[n+1] | bsum i[128]
    char* ws = (char*)d_ws;
    unsigned short* Wt1s = (unsigned short*)ws;
    unsigned short* Wt2s = Wt1s + D * D;
    float* degree       = (float*)(Wt2s + D * D);
    float2* pairs       = (float2*)(degree + n);
    unsigned short* hbf = (unsigned short*)(pairs + E);
    int* count          = (int*)(hbf + (size_t)n * D);
    int* selfc          = count + n;
    int* row_ptr        = selfc + n;
    int* block_sums     = row_ptr + (n + 1);

    hipMemsetAsync(count, 0, (size_t)2 * n * sizeof(int), stream);  // count+selfc

    const int eb = (E + 255) / 256;              // 2344
    k_prep_count<<<64 + eb, 256, 0, stream>>>(W1, W2, Wt1s, Wt2s,
                                              edge_src, edge_dst, count, selfc, E);

    k_scan_local<<<nb, 256, 0, stream>>>(count, selfc, indp, degree, row_ptr, block_sums, n);
    k_scan_blocks<<<1, 128, 0, stream>>>(block_sums, nb);

    const int nm = (n + 127) / 128;              // 782
    k_mlp_place<<<nm + eb, 256, 0, stream>>>(feat, Wt1s, Wt2s, b1, b2, hbf, n, nm,
                                             edge_src, edge_dst, W_edge, degree,
                                             row_ptr, block_sums, count, pairs, E);

    long long athreads = (long long)n * 16;
    k_aggregate<<<(int)((athreads + 255) / 256), 256, 0, stream>>>(row_ptr, block_sums, pairs,
                                                                   hbf, (float*)d_out, n, E);
}